// Round 4
// baseline (289.129 us; speedup 1.0000x reference)
//
#include <hip/hip_runtime.h>
#include <hip/hip_bf16.h>
#include <cstdint>
#include <cstddef>

#define EMBED 768
#define NHEAD 32
#define HDIM 24
#define DPAD 32          // padded head dim = MFMA K
#define BATCH 4
#define SEQ 512
#define WCOLS 1632       // 768 q | 768 k | 96 vw
#define NPADCOL 1664     // padded to 26*64

typedef __attribute__((ext_vector_type(8))) short short8;
typedef __attribute__((ext_vector_type(4))) float f32x4;

static __device__ __forceinline__ unsigned short f2b(float v) {
    __hip_bfloat16 h = __float2bfloat16(v);
    return *reinterpret_cast<unsigned short*>(&h);
}

// ---------------------------------------------------------------------------
// prep_w: WcT[j][e] (bf16, 1664x768) = row j of fused output matrix
//   j<768: Wq[j][e]*scal | j<1536: Wk[j-768][e] | j<1632: (Wv^T@Wf)[j] | 0
// Thread 0 of each block also computes bcat[j] (fused bias prep).
// ---------------------------------------------------------------------------
__global__ __launch_bounds__(256) void prep_w_kernel(
    const float* __restrict__ Wq, const float* __restrict__ Wk,
    const float* __restrict__ Wv, const float* __restrict__ Wf,
    const float* __restrict__ bq, const float* __restrict__ bkv,
    const float* __restrict__ bv,
    unsigned short* __restrict__ WcT, float* __restrict__ bcat)
{
    const float sc = 0.20412414523193154f;  // 24^-0.5
    int j = blockIdx.x;
    #pragma unroll
    for (int rep = 0; rep < 3; ++rep) {
        int e = rep * 256 + threadIdx.x;
        float v;
        if (j < 768) {
            v = Wq[(size_t)j * EMBED + e] * sc;
        } else if (j < 1536) {
            v = Wk[(size_t)(j - 768) * EMBED + e];
        } else if (j < WCOLS) {
            int jc = j - 1536, h = jc / 3, c = jc - h * 3;
            float s = 0.f;
            #pragma unroll
            for (int d = 0; d < HDIM; ++d)
                s = fmaf(Wv[(size_t)(h * HDIM + d) * EMBED + e],
                         Wf[c * EMBED + h * HDIM + d], s);
            v = s;
        } else {
            v = 0.f;
        }
        WcT[(size_t)j * EMBED + e] = f2b(v);
    }
    if (threadIdx.x == 0) {
        float v = 0.f;
        if (j < 768) v = bq[j] * sc;
        else if (j < 1536) v = bkv[j - 768];
        else if (j < WCOLS) {
            int jc = j - 1536, h = jc / 3, c = jc - h * 3;
            float s = 0.f;
            #pragma unroll
            for (int d = 0; d < HDIM; ++d)
                s = fmaf(bv[h * HDIM + d], Wf[c * EMBED + h * HDIM + d], s);
            v = s;
        }
        bcat[j] = v;
    }
}

// ---------------------------------------------------------------------------
// dtr: delta [b][n][m][c] -> [b][c][n][m]  (unit-stride m for attn loads)
// ---------------------------------------------------------------------------
__global__ __launch_bounds__(256) void dtr_kernel(
    const float* __restrict__ delta, float* __restrict__ dtr)
{
    size_t u = (size_t)blockIdx.x * 256 + threadIdx.x;  // (b,n,m) linear
    int m = (int)(u & 511);
    int n = (int)((u >> 9) & 511);
    int b = (int)(u >> 18);
    float d0 = delta[u * 3 + 0];
    float d1 = delta[u * 3 + 1];
    float d2 = delta[u * 3 + 2];
    dtr[((size_t)(b * 3 + 0) * SEQ + n) * SEQ + m] = d0;
    dtr[((size_t)(b * 3 + 1) * SEQ + n) * SEQ + m] = d1;
    dtr[((size_t)(b * 3 + 2) * SEQ + n) * SEQ + m] = d2;
}

// ---------------------------------------------------------------------------
// MFMA GEMM: C[2048][1664] = bf16(query)[2048][768] @ WcT^T (+bcat).
// 64x64 tile, 4 waves (2x2), BK=32. Register prefetch of tile kt+1 issued
// BEFORE computing tile kt; double-buffered LDS -> ONE barrier per K-step.
// A is f32 (query) converted to bf16 while staging (qconv fused away).
// LSTR=40 shorts (80B rows): 16B-aligned b128 LDS ops, 2-way max conflict.
// Epilogue scatters: qp/kp bf16 [bh][n][32] (d<24), vwb f32 [bh][c][m].
// ---------------------------------------------------------------------------
#define LSTR 40
__global__ __launch_bounds__(256) void gemm_kernel(
    const float* __restrict__ Aq, const unsigned short* __restrict__ WcT,
    const float* __restrict__ bcat,
    unsigned short* __restrict__ qp, unsigned short* __restrict__ kp,
    float* __restrict__ vwb)
{
    __shared__ short As[2][64 * LSTR];
    __shared__ short Bs[2][64 * LSTR];
    int t = threadIdx.x;
    int lane = t & 63, wv = t >> 6;
    int l15 = lane & 15, lg = lane >> 4;
    int m0 = blockIdx.x * 64, n0 = blockIdx.y * 64;
    int wm = (wv >> 1) * 32, wn = (wv & 1) * 32;

    f32x4 acc[2][2];
    #pragma unroll
    for (int i = 0; i < 2; ++i)
        #pragma unroll
        for (int j = 0; j < 2; ++j) acc[i][j] = (f32x4){0.f, 0.f, 0.f, 0.f};

    int sr = t >> 2;            // 0..63 (row within tile)
    int sc8 = (t & 3) * 8;      // 0,8,16,24 (k-element offset)
    const float* Ag = Aq + (size_t)(m0 + sr) * EMBED + sc8;
    const unsigned short* Bg = WcT + (size_t)(n0 + sr) * EMBED + sc8;
    int lidx = sr * LSTR + sc8;

    short8 fa, fb;
    {   // tile 0
        float4 a0 = *(const float4*)(Ag);
        float4 a1 = *(const float4*)(Ag + 4);
        union { unsigned short u[8]; short8 v; } r;
        r.u[0] = f2b(a0.x); r.u[1] = f2b(a0.y); r.u[2] = f2b(a0.z); r.u[3] = f2b(a0.w);
        r.u[4] = f2b(a1.x); r.u[5] = f2b(a1.y); r.u[6] = f2b(a1.z); r.u[7] = f2b(a1.w);
        fa = r.v;
        fb = *(const short8*)(Bg);
    }
    *(short8*)&As[0][lidx] = fa;
    *(short8*)&Bs[0][lidx] = fb;
    __syncthreads();

    for (int kt = 0; kt < EMBED / 32; ++kt) {
        int cur = kt & 1;
        bool more = (kt + 1) < EMBED / 32;
        if (more) {   // issue next tile's global loads FIRST (prefetch)
            float4 a0 = *(const float4*)(Ag + (kt + 1) * 32);
            float4 a1 = *(const float4*)(Ag + (kt + 1) * 32 + 4);
            fb = *(const short8*)(Bg + (size_t)(kt + 1) * 32);
            union { unsigned short u[8]; short8 v; } r;
            r.u[0] = f2b(a0.x); r.u[1] = f2b(a0.y); r.u[2] = f2b(a0.z); r.u[3] = f2b(a0.w);
            r.u[4] = f2b(a1.x); r.u[5] = f2b(a1.y); r.u[6] = f2b(a1.z); r.u[7] = f2b(a1.w);
            fa = r.v;
        }
        short8 af[2], bfr[2];
        #pragma unroll
        for (int i = 0; i < 2; ++i) {
            af[i]  = *(const short8*)&As[cur][(wm + i * 16 + l15) * LSTR + lg * 8];
            bfr[i] = *(const short8*)&Bs[cur][(wn + i * 16 + l15) * LSTR + lg * 8];
        }
        #pragma unroll
        for (int mt = 0; mt < 2; ++mt)
            #pragma unroll
            for (int nt = 0; nt < 2; ++nt)
                acc[mt][nt] = __builtin_amdgcn_mfma_f32_16x16x32_bf16(
                    af[mt], bfr[nt], acc[mt][nt], 0, 0, 0);
        if (more) {
            *(short8*)&As[cur ^ 1][lidx] = fa;
            *(short8*)&Bs[cur ^ 1][lidx] = fb;
            __syncthreads();
        }
    }

    #pragma unroll
    for (int mt = 0; mt < 2; ++mt) {
        #pragma unroll
        for (int nt = 0; nt < 2; ++nt) {
            #pragma unroll
            for (int r = 0; r < 4; ++r) {
                int gm = m0 + wm + mt * 16 + lg * 4 + r;   // token row
                int gn = n0 + wn + nt * 16 + l15;          // output col
                float v = acc[mt][nt][r] + bcat[gn];
                int b = gm >> 9, ns = gm & 511;
                if (gn < 768) {
                    int h = gn / 24, d = gn - h * 24;
                    qp[((size_t)(b * NHEAD + h) * SEQ + ns) * DPAD + d] = f2b(v);
                } else if (gn < 1536) {
                    int j2 = gn - 768, h = j2 / 24, d = j2 - h * 24;
                    kp[((size_t)(b * NHEAD + h) * SEQ + ns) * DPAD + d] = f2b(v);
                } else if (gn < WCOLS) {
                    int jc = gn - 1536, h = jc / 3, c = jc - h * 3;
                    vwb[((size_t)(b * NHEAD + h) * 3 + c) * SEQ + ns] = v;
                }
            }
        }
    }
}

__global__ __launch_bounds__(256) void init_out_kernel(
    const float* __restrict__ bf, float* __restrict__ out)
{
    int i = blockIdx.x * 256 + threadIdx.x;
    if (i < BATCH * SEQ * 3) out[i] = bf[i - (i / 3) * 3];
}

// ---------------------------------------------------------------------------
// Fused attention+force v2: block = (16 q-rows, b, 8-head group), 512 thr,
// WAVE = ONE FULL HEAD (all m in 0..512). Single pass, deferred division:
//   facu[r][c] = sum_m e * vw[c][m] * dtr[c][n][m];  den[r] = sum_m e
//   fac = facu / den   (softmax division deferred -- no ep storage)
// Per mt: 1 MFMA (S-tile), e = exp(S+bias), accumulate. ZERO barriers and
// ZERO LDS in the head loop; in-wave 16-lane shfl reduce at the end.
// ---------------------------------------------------------------------------
__global__ __launch_bounds__(512) void attn_kernel(
    const unsigned short* __restrict__ qp, const unsigned short* __restrict__ kp,
    const float* __restrict__ vwb, const float* __restrict__ bias,
    const float* __restrict__ dtr, float* __restrict__ out)
{
    __shared__ float wred[8][16][3];
    int t = threadIdx.x, lane = t & 63, w = t >> 6;
    int l15 = lane & 15, lg = lane >> 4;
    int nbase = blockIdx.x * 16;
    int b = blockIdx.y;
    int bh = b * NHEAD + blockIdx.z * 8 + w;

    short8 aq = *(const short8*)(qp + ((size_t)bh * SEQ + nbase + l15) * DPAD + lg * 8);

    const unsigned short* kbase = kp + (size_t)bh * SEQ * DPAD + lg * 8;
    const float* vw0   = vwb + (size_t)bh * 3 * SEQ + l15;
    const float* bbase = bias + ((size_t)bh * SEQ + nbase + lg * 4) * SEQ + l15;
    const float* dbase = dtr + (size_t)b * 3 * SEQ * SEQ
                             + (size_t)(nbase + lg * 4) * SEQ + l15;

    float den[4] = {0.f, 0.f, 0.f, 0.f};
    float facu[4][3];
    #pragma unroll
    for (int r = 0; r < 4; ++r) { facu[r][0] = 0.f; facu[r][1] = 0.f; facu[r][2] = 0.f; }

    #pragma unroll 2
    for (int mt = 0; mt < SEQ / 16; ++mt) {
        int moff = mt * 16;
        short8 bk = *(const short8*)(kbase + (size_t)(moff + l15) * DPAD);
        f32x4 z = {0.f, 0.f, 0.f, 0.f};
        f32x4 acc = __builtin_amdgcn_mfma_f32_16x16x32_bf16(aq, bk, z, 0, 0, 0);
        float v0 = vw0[moff];
        float v1 = vw0[SEQ + moff];
        float v2 = vw0[2 * SEQ + moff];
        #pragma unroll
        for (int r = 0; r < 4; ++r) {
            float e = __expf(acc[r] + bbase[(size_t)r * SEQ + moff]);
            den[r] += e;
            facu[r][0] = fmaf(e * v0, dbase[(size_t)r * SEQ + moff], facu[r][0]);
            facu[r][1] = fmaf(e * v1, dbase[(size_t)SEQ * SEQ + r * SEQ + moff], facu[r][1]);
            facu[r][2] = fmaf(e * v2, dbase[(size_t)2 * SEQ * SEQ + r * SEQ + moff], facu[r][2]);
        }
    }

    // in-wave m-reduction (within each 16-lane group), then deferred divide
    #pragma unroll
    for (int r = 0; r < 4; ++r) {
        #pragma unroll
        for (int o = 1; o <= 8; o <<= 1) {
            den[r]     += __shfl_xor(den[r], o);
            facu[r][0] += __shfl_xor(facu[r][0], o);
            facu[r][1] += __shfl_xor(facu[r][1], o);
            facu[r][2] += __shfl_xor(facu[r][2], o);
        }
        float rd = __builtin_amdgcn_rcpf(den[r]);
        facu[r][0] *= rd; facu[r][1] *= rd; facu[r][2] *= rd;
    }
    if (l15 == 0) {
        #pragma unroll
        for (int r = 0; r < 4; ++r) {
            wred[w][lg * 4 + r][0] = facu[r][0];
            wred[w][lg * 4 + r][1] = facu[r][1];
            wred[w][lg * 4 + r][2] = facu[r][2];
        }
    }
    __syncthreads();
    if (t < 48) {
        int n = t / 3, c = t - n * 3;
        float s = 0.f;
        #pragma unroll
        for (int ww = 0; ww < 8; ++ww) s += wred[ww][n][c];
        atomicAdd(&out[(size_t)(b * SEQ + nbase + n) * 3 + c], s);
    }
}

// ---------------------------------------------------------------------------
extern "C" void kernel_launch(void* const* d_in, const int* in_sizes, int n_in,
                              void* d_out, int out_size, void* d_ws, size_t ws_size,
                              hipStream_t stream)
{
    const float* query = (const float*)d_in[0];
    const float* attn_bias = (const float*)d_in[1];
    const float* delta = (const float*)d_in[2];
    const float* Wq = (const float*)d_in[3];
    const float* bq = (const float*)d_in[4];
    const float* Wk = (const float*)d_in[5];
    const float* bk = (const float*)d_in[6];
    const float* Wv = (const float*)d_in[7];
    const float* bv = (const float*)d_in[8];
    const float* Wf = (const float*)d_in[9];
    const float* bf = (const float*)d_in[10];
    float* out = (float*)d_out;

    uint8_t* p = (uint8_t*)d_ws;
    unsigned short* qp  = (unsigned short*)p; p += (size_t)BATCH * NHEAD * SEQ * DPAD * 2;
    unsigned short* kp  = (unsigned short*)p; p += (size_t)BATCH * NHEAD * SEQ * DPAD * 2;
    unsigned short* WcT = (unsigned short*)p; p += (size_t)NPADCOL * EMBED * 2;
    float* bcat = (float*)p;                  p += (size_t)NPADCOL * 4;
    float* vwb  = (float*)p;                  p += (size_t)BATCH * NHEAD * 3 * SEQ * 4;
    float* dtr  = (float*)p;                  p += (size_t)BATCH * 3 * SEQ * SEQ * 4;

    // zero q/k pads (d=24..31) -- gemm epilogue writes only d<24
    hipMemsetAsync(qp, 0, (size_t)BATCH * NHEAD * SEQ * DPAD * 2 * 2, stream);

    hipLaunchKernelGGL(prep_w_kernel, dim3(NPADCOL), dim3(256), 0, stream,
                       Wq, Wk, Wv, Wf, bq, bk, bv, WcT, bcat);
    hipLaunchKernelGGL(dtr_kernel, dim3((BATCH * SEQ * SEQ) / 256), dim3(256),
                       0, stream, delta, dtr);
    hipLaunchKernelGGL(gemm_kernel, dim3((BATCH * SEQ) / 64, NPADCOL / 64),
                       dim3(256), 0, stream, query, WcT, bcat, qp, kp, vwb);
    hipLaunchKernelGGL(init_out_kernel, dim3((BATCH * SEQ * 3 + 255) / 256),
                       dim3(256), 0, stream, bf, out);
    hipLaunchKernelGGL(attn_kernel, dim3(SEQ / 16, BATCH, 4), dim3(512), 0, stream,
                       qp, kp, vwb, attn_bias, dtr, out);
}